// Round 15
// baseline (788.412 us; speedup 1.0000x reference)
//
#include <hip/hip_runtime.h>
#include <hip/hip_bf16.h>
#include <math.h>

#define NB 8
#define NT 2048
#define NC 768
#define ROWS (NB*NT)   // 16384

typedef __attribute__((ext_vector_type(8))) short s8v;   // 8 bf16 (4 VGPRs)
typedef __attribute__((ext_vector_type(4))) float f4v;   // 4 fp32 acc

__device__ __forceinline__ unsigned short f2b(float f) {  // fp32->bf16 RNE
    unsigned u = __builtin_bit_cast(unsigned, f);
    return (unsigned short)((u + 0x7FFFu + ((u >> 16) & 1u)) >> 16);
}

// async global->LDS DMA, 16B per lane. LDS dest = wave-uniform base + lane*16.
__device__ __forceinline__ void gll16(const ushort* g, ushort* l) {
    __builtin_amdgcn_global_load_lds(
        (const __attribute__((address_space(1))) void*)g,
        (__attribute__((address_space(3))) void*)l, 16, 0, 0);
}

// counted vmcnt wait (T4): wait until <=N of this wave's VMEM ops remain.
template<int N> __device__ __forceinline__ void waitcnt_vm() {
    if constexpr (N == 3)      asm volatile("s_waitcnt vmcnt(3)" ::: "memory");
    else if constexpr (N == 4) asm volatile("s_waitcnt vmcnt(4)" ::: "memory");
    else if constexpr (N == 6) asm volatile("s_waitcnt vmcnt(6)" ::: "memory");
    else                       asm volatile("s_waitcnt vmcnt(0)" ::: "memory");
}
__device__ __forceinline__ void hw_barrier() {   // barrier + compiler mem fence
    asm volatile("s_barrier" ::: "memory");
}

// T1 XCD-aware block swizzle (verified R14: dual-GLU FETCH 75->34.5 MB).
// Bijective iff nwg%8==0 (all our grids).
__device__ __forceinline__ void xcd_swz(int& bx, int& by, int& bz) {
    int gx = gridDim.x, gy = gridDim.y;
    int nwg = gx * gy * (int)gridDim.z;
    int flat = bx + gx * (by + gy * bz);
    int cpx = nwg >> 3;
    int s = (flat & 7) * cpx + (flat >> 3);
    bx = s % gx; int rem = s / gx;
    by = rem % gy; bz = rem / gy;
}

// ---------------- MFMA GEMM: C = A@B^T-layout (+bias)(+resid) ----------------
// A bf16 [M,K]; B bf16 [N,K] outer-major. Tile 128xTN, 4 waves.
// Counted-vmcnt double-buffered K-loop (T3+T4, verified R12/R14). This round:
// ALL per-lane addressing hoisted out of the K-loop — LP source pointers
// advance by +32/step; LDS dests and the swizzled ds_read offsets are
// precomputed. Sync structure (stage -> vmcnt(LP) -> barrier -> mfma ->
// barrier) is byte-identical to the verified template.
// EPI: 0=bf16+bias; 3=f32 resid in-place; 4=resid f32->bf16 out; 5=f32+bias; 6=atomic f32
template<int TN, int EPI, bool HASBIAS, bool SPLITK>
__global__ __launch_bounds__(256) void gemm_mfma(
    const ushort* __restrict__ A, const ushort* __restrict__ Bt,
    float* __restrict__ Cf, ushort* __restrict__ Cb,
    int M, int N, int K, int lda, int ldb, int ldc,
    long sA, long sB, long sC, const float* __restrict__ bias)
{
    constexpr int WM = (TN == 128) ? 64 : 32;
    constexpr int TI = WM / 16;               // 4 or 2
    constexpr int BN = TN * 32;
    constexpr int CB = TN / 64;               // B chunks per wave
    constexpr int LP = 2 + CB;                // gll16 per wave per K-step
    int bx = blockIdx.x, by = blockIdx.y, bz = blockIdx.z;
    xcd_swz(bx, by, bz);
    int zz = bz;
    int z  = SPLITK ? (zz >> 2) : zz;
    int kb = SPLITK ? (zz & 3) * (K >> 2) : 0;
    int ke = SPLITK ? kb + (K >> 2) : K;
    const ushort* Az = A + (long)z * sA;
    const ushort* Bz = Bt + (long)z * sB;
    float*  Cfz = Cf ? Cf + (long)z * sC : nullptr;
    ushort* Cbz = Cb ? Cb + (long)z * sC : nullptr;

    int m0 = by * 128, n0 = bx * TN;
    __shared__ alignas(16) ushort Al[8192];        // 2 x 128x32
    __shared__ alignas(16) ushort Bl[2 * BN];
    int t = threadIdx.x;
    int lane = t & 63, w = t >> 6;
    int wm = (TN == 128) ? (w >> 1) * 64 : w * 32;
    int wn = (TN == 128) ? (w & 1) * 64 : 0;
    int fr = lane & 15, q = lane >> 4;

    // ---- hoisted per-lane staging pointers (advance +32/K-step) ----
    int rs = lane >> 2, cb = lane & 3;
    const ushort* srcA[2]; ushort* dstA[2];
    const ushort* srcB[CB]; ushort* dstB[CB];
#pragma unroll
    for (int i = 0; i < 2; i++) {
        int ii = w + 4 * i, row = ii * 16 + rs;
        int kc = (cb ^ ((row >> 1) & 3)) << 3;
        srcA[i] = Az + (long)(m0 + row) * lda + kb + kc;
        dstA[i] = Al + ii * 512;
    }
#pragma unroll
    for (int i = 0; i < CB; i++) {
        int ii = w + 4 * i, row = ii * 16 + rs;
        int kc = (cb ^ ((row >> 1) & 3)) << 3;
        srcB[i] = Bz + (long)(n0 + row) * ldb + kb + kc;
        dstB[i] = Bl + ii * 512;
    }
    auto stage_adv = [&](int b) {
#pragma unroll
        for (int i = 0; i < 2; i++) { gll16(srcA[i], dstA[i] + b * 4096); srcA[i] += 32; }
#pragma unroll
        for (int i = 0; i < CB; i++) { gll16(srcB[i], dstB[i] + b * BN); srcB[i] += 32; }
    };

    // ---- hoisted swizzled ds_read byte offsets ----
    int offA[TI], offB[4];
#pragma unroll
    for (int ti = 0; ti < TI; ti++) {
        int r = wm + ti * 16 + fr;
        offA[ti] = r * 32 + ((q ^ ((r >> 1) & 3)) << 3);
    }
#pragma unroll
    for (int tj = 0; tj < 4; tj++) {
        int r = wn + tj * 16 + fr;
        offB[tj] = r * 32 + ((q ^ ((r >> 1) & 3)) << 3);
    }

    f4v acc[TI][4];
#pragma unroll
    for (int i = 0; i < TI; i++)
#pragma unroll
        for (int j = 0; j < 4; j++) acc[i][j] = (f4v)(0.0f);

    auto frag_mfma = [&](const ushort* AB, const ushort* BB) {
        s8v af[TI], bf[4];
#pragma unroll
        for (int ti = 0; ti < TI; ti++) af[ti] = *(const s8v*)&AB[offA[ti]];
#pragma unroll
        for (int tj = 0; tj < 4; tj++) bf[tj] = *(const s8v*)&BB[offB[tj]];
#pragma unroll
        for (int ti = 0; ti < TI; ti++)
#pragma unroll
            for (int tj = 0; tj < 4; tj++)
                acc[ti][tj] = __builtin_amdgcn_mfma_f32_16x16x32_bf16(
                    af[ti], bf[tj], acc[ti][tj], 0, 0, 0);
    };

    int nt = (ke - kb) >> 5;
    stage_adv(0);
    int cur = 0;
    for (int it = 0; it + 1 < nt; ++it) {
        stage_adv(cur ^ 1);
        waitcnt_vm<LP>();          // tile it landed; tile it+1 stays in flight
        hw_barrier();
        frag_mfma(Al + cur * 4096, Bl + cur * BN);
        hw_barrier();              // WAR guard for buffer recycle
        cur ^= 1;
    }
    waitcnt_vm<0>();               // last tile's loads
    hw_barrier();
    frag_mfma(Al + cur * 4096, Bl + cur * BN);

    int cr0 = q * 4;  // C/D: col = lane&15, row = (lane>>4)*4 + reg
#pragma unroll
    for (int ti = 0; ti < TI; ti++) {
#pragma unroll
        for (int tj = 0; tj < 4; tj++) {
            int n = n0 + wn + tj * 16 + fr;
            float bv = HASBIAS ? bias[n] : 0.0f;
#pragma unroll
            for (int r = 0; r < 4; r++) {
                int m = m0 + wm + ti * 16 + cr0 + r;
                long idx = (long)m * ldc + n;
                float v = acc[ti][tj][r] + bv;
                if (EPI == 0) {
                    Cbz[idx] = f2b(v);
                } else if (EPI == 5) {
                    Cfz[idx] = v;
                } else if (EPI == 6) {
                    __hip_atomic_fetch_add(&Cfz[idx], v, __ATOMIC_RELAXED,
                                           __HIP_MEMORY_SCOPE_AGENT);
                } else {  // 3, 4
                    v += Cfz[idx];
                    if (EPI == 3) Cfz[idx] = v;      // x2 f32 (read by LN2 + style resid)
                    if (EPI == 4) Cbz[idx] = f2b(v); // x3 f32 copy is never read: skip store
                }
            }
        }
    }
}

// ---------------- fused GLU GEMM: out = (A@Wv+bv)*sigmoid(A@Wg+bg)*s ----------------
// A bf16 (DMA-staged). B = W^T bf16 [2Nh, K]. grid.z selects pair.
// Same hoisted-addressing counted-vmcnt schedule as gemm_mfma.
template<int TN, bool HAS_S>
__global__ __launch_bounds__(256) void gemm_glu_mfma(
    const ushort* __restrict__ A,
    const ushort* __restrict__ Bt0, const ushort* __restrict__ Bt1,
    ushort* __restrict__ C0, ushort* __restrict__ C1,
    int M, int Nh, int K, int lda,
    const float* __restrict__ bias0, const float* __restrict__ bias1,
    const float* __restrict__ s0, const float* __restrict__ s1, int bofs)
{
    constexpr int WM = (TN == 128) ? 64 : 32;
    constexpr int TI = WM / 16;
    constexpr int BN = TN * 32;
    constexpr int CB = TN / 64;
    constexpr int LP = 2 + 2 * CB;            // gll16 per wave per K-step
    int bx = blockIdx.x, by = blockIdx.y, bz = blockIdx.z;
    xcd_swz(bx, by, bz);
    int z = bz;
    const ushort* Bt = z ? Bt1 : Bt0;
    ushort* Cb = z ? C1 : C0;
    const float* bias = z ? bias1 : bias0;
    const float* s = z ? s1 : s0;

    int m0 = by * 128, n0 = bx * TN;
    __shared__ alignas(16) ushort Al[8192];
    __shared__ alignas(16) ushort B1[2 * BN];
    __shared__ alignas(16) ushort B2[2 * BN];
    int t = threadIdx.x;
    int lane = t & 63, w = t >> 6;
    int wm = (TN == 128) ? (w >> 1) * 64 : w * 32;
    int wn = (TN == 128) ? (w & 1) * 64 : 0;
    int fr = lane & 15, q = lane >> 4;

    // ---- hoisted per-lane staging pointers ----
    int rs = lane >> 2, cbn = lane & 3;
    const ushort* srcA[2]; ushort* dstA[2];
    const ushort* srcU[CB]; ushort* dstU[CB];
    const ushort* srcV[CB]; ushort* dstV[CB];
#pragma unroll
    for (int i = 0; i < 2; i++) {
        int ii = w + 4 * i, row = ii * 16 + rs;
        int kc = (cbn ^ ((row >> 1) & 3)) << 3;
        srcA[i] = A + (long)(m0 + row) * lda + kc;
        dstA[i] = Al + ii * 512;
    }
#pragma unroll
    for (int i = 0; i < CB; i++) {
        int ii = w + 4 * i, row = ii * 16 + rs;
        int kc = (cbn ^ ((row >> 1) & 3)) << 3;
        srcU[i] = Bt + (long)(n0 + row) * K + kc;
        srcV[i] = Bt + (long)(Nh + n0 + row) * K + kc;
        dstU[i] = B1 + ii * 512;
        dstV[i] = B2 + ii * 512;
    }
    auto stage_adv = [&](int b) {
#pragma unroll
        for (int i = 0; i < CB; i++) { gll16(srcU[i], dstU[i] + b * BN); srcU[i] += 32; }
#pragma unroll
        for (int i = 0; i < CB; i++) { gll16(srcV[i], dstV[i] + b * BN); srcV[i] += 32; }
#pragma unroll
        for (int i = 0; i < 2; i++)  { gll16(srcA[i], dstA[i] + b * 4096); srcA[i] += 32; }
    };

    // ---- hoisted swizzled ds_read byte offsets ----
    int offA[TI], offB[4];
#pragma unroll
    for (int ti = 0; ti < TI; ti++) {
        int r = wm + ti * 16 + fr;
        offA[ti] = r * 32 + ((q ^ ((r >> 1) & 3)) << 3);
    }
#pragma unroll
    for (int tj = 0; tj < 4; tj++) {
        int r = wn + tj * 16 + fr;
        offB[tj] = r * 32 + ((q ^ ((r >> 1) & 3)) << 3);
    }

    f4v acc1[TI][4], acc2[TI][4];
#pragma unroll
    for (int i = 0; i < TI; i++)
#pragma unroll
        for (int j = 0; j < 4; j++) { acc1[i][j] = (f4v)(0.0f); acc2[i][j] = (f4v)(0.0f); }

    auto frag_mfma = [&](const ushort* AB, const ushort* BB1, const ushort* BB2) {
        s8v af[TI], b1f[4], b2f[4];
#pragma unroll
        for (int ti = 0; ti < TI; ti++) af[ti] = *(const s8v*)&AB[offA[ti]];
#pragma unroll
        for (int tj = 0; tj < 4; tj++) {
            b1f[tj] = *(const s8v*)&BB1[offB[tj]];
            b2f[tj] = *(const s8v*)&BB2[offB[tj]];
        }
#pragma unroll
        for (int ti = 0; ti < TI; ti++)
#pragma unroll
            for (int tj = 0; tj < 4; tj++) {
                acc1[ti][tj] = __builtin_amdgcn_mfma_f32_16x16x32_bf16(af[ti], b1f[tj], acc1[ti][tj], 0, 0, 0);
                acc2[ti][tj] = __builtin_amdgcn_mfma_f32_16x16x32_bf16(af[ti], b2f[tj], acc2[ti][tj], 0, 0, 0);
            }
    };

    int nt = K >> 5;
    stage_adv(0);
    int cur = 0;
    for (int it = 0; it + 1 < nt; ++it) {
        stage_adv(cur ^ 1);
        waitcnt_vm<LP>();          // tile it landed; tile it+1 stays in flight
        hw_barrier();
        frag_mfma(Al + cur * 4096, B1 + cur * BN, B2 + cur * BN);
        hw_barrier();              // WAR guard for buffer recycle
        cur ^= 1;
    }
    waitcnt_vm<0>();
    hw_barrier();
    frag_mfma(Al + cur * 4096, B1 + cur * BN, B2 + cur * BN);

    int cr0 = q * 4;
#pragma unroll
    for (int ti = 0; ti < TI; ti++) {
        int bb = ((m0 + wm + ti * 16 + cr0) >> 11) + bofs;   // batch = row/2048
#pragma unroll
        for (int tj = 0; tj < 4; tj++) {
            int n = n0 + wn + tj * 16 + fr;
            float bv = bias[n], bg = bias[Nh + n];
            float sv = HAS_S ? s[(long)bb * Nh + n] : 1.0f;
#pragma unroll
            for (int r = 0; r < 4; r++) {
                int m = m0 + wm + ti * 16 + cr0 + r;
                float vv = acc1[ti][tj][r] + bv;
                float gg = acc2[ti][tj][r] + bg;
                float a = vv * (1.0f / (1.0f + __expf(-gg)));
                if (HAS_S) a *= sv;
                Cb[(long)m * Nh + n] = f2b(a);
            }
        }
    }
}

// ---------------- gelu + cast fp32 -> bf16 (elementwise, float4) ----------------
__global__ __launch_bounds__(256) void gelu_cast_kernel(const float* __restrict__ in,
                                                        ushort* __restrict__ out) {
    int i4 = (blockIdx.x * 256 + threadIdx.x) * 4;
    float4 v = *(const float4*)(in + i4);
    ushort4 o;
    o.x = f2b(0.5f * v.x * (1.0f + erff(v.x * 0.70710678118654752440f)));
    o.y = f2b(0.5f * v.y * (1.0f + erff(v.y * 0.70710678118654752440f)));
    o.z = f2b(0.5f * v.z * (1.0f + erff(v.z * 0.70710678118654752440f)));
    o.w = f2b(0.5f * v.w * (1.0f + erff(v.w * 0.70710678118654752440f)));
    *(ushort4*)(out + i4) = o;
}

// ---------------- transpose: src [R,C] (batched) -> dst bf16 [C,R] ----------------
template<bool SRC_F32>
__global__ __launch_bounds__(256) void transpose_kernel(const void* __restrict__ src,
                                                        ushort* __restrict__ dst,
                                                        int R, int C, long sS, long sD) {
    int z = blockIdx.z;
    const void* S = SRC_F32 ? (const void*)((const float*)src + (long)z * sS)
                            : (const void*)((const ushort*)src + (long)z * sS);
    ushort* D = dst + (long)z * sD;
    int r0 = blockIdx.y * 64, c0 = blockIdx.x * 64;
    __shared__ ushort T[64][68];
    int t = threadIdx.x;
#pragma unroll
    for (int p = 0; p < 4; p++) {
        int e = p * 256 + t;
        int row = e >> 4, cc = (e & 15) * 4;
        ushort4 v;
        if (SRC_F32) {
            float4 f = *(const float4*)((const float*)S + (long)(r0 + row) * C + c0 + cc);
            v.x = f2b(f.x); v.y = f2b(f.y); v.z = f2b(f.z); v.w = f2b(f.w);
        } else {
            v = *(const ushort4*)((const ushort*)S + (long)(r0 + row) * C + c0 + cc);
        }
        *(ushort4*)&T[row][cc] = v;
    }
    __syncthreads();
#pragma unroll
    for (int p = 0; p < 4; p++) {
        int e = p * 256 + t;
        int crow = e >> 4, rr = (e & 15) * 4;
        ushort4 o;
        o.x = T[rr + 0][crow]; o.y = T[rr + 1][crow];
        o.z = T[rr + 2][crow]; o.w = T[rr + 3][crow];
        *(ushort4*)&D[(long)(c0 + crow) * R + r0 + rr] = o;
    }
}

// ---------------- merged prep: 8 weight cast+transposes + style vectors ----------------
// blocks [0,23040): castT segments; [23040,23112): svec (72 blocks).
__global__ __launch_bounds__(256) void prep_kernel(
    const float* __restrict__ g1_W, ushort* __restrict__ g1t,
    const float* __restrict__ g2_W, ushort* __restrict__ g2t,
    const float* __restrict__ m1_W, ushort* __restrict__ m1t,
    const float* __restrict__ m2_W, ushort* __restrict__ m2t,
    const float* __restrict__ gs_W, ushort* __restrict__ gst,
    const float* __restrict__ ms_W, ushort* __restrict__ mst,
    const float* __restrict__ r1_W, ushort* __restrict__ r1t,
    const float* __restrict__ r2_W, ushort* __restrict__ r2t,
    const float* __restrict__ w,
    const float* __restrict__ s1W, const float* __restrict__ s1b,
    const float* __restrict__ s2W, const float* __restrict__ s2b,
    const float* __restrict__ ssW, const float* __restrict__ ssb,
    float* __restrict__ sout)
{
    int b = blockIdx.x, t = threadIdx.x;
    if (b < 23040) {
        const float* W; ushort* Wt; int K, N, lo;
        if      (b < 2304)  { W = g1_W; Wt = g1t; K = 768;  N = 768;  lo = 0; }
        else if (b < 4608)  { W = g2_W; Wt = g2t; K = 768;  N = 768;  lo = 2304; }
        else if (b < 5184)  { W = m1_W; Wt = m1t; K = 384;  N = 384;  lo = 4608; }
        else if (b < 5760)  { W = m2_W; Wt = m2t; K = 384;  N = 384;  lo = 5184; }
        else if (b < 14976) { W = gs_W; Wt = gst; K = 768;  N = 3072; lo = 5760; }
        else if (b < 19584) { W = ms_W; Wt = mst; K = 1536; N = 768;  lo = 14976; }
        else if (b < 21888) { W = r1_W; Wt = r1t; K = 768;  N = 768;  lo = 19584; }
        else                { W = r2_W; Wt = r2t; K = 384;  N = 768;  lo = 21888; }
        int local = b - lo, bx = K >> 6;
        int byi = local / bx, bxi = local - byi * bx;
        int k = bxi * 64 + (t & 63), n = byi * 4 + (t >> 6);
        Wt[(long)n * K + k] = f2b(W[(long)k * N + n]);
    } else {
        int gid = (b - 23040) * 256 + t;   // 0..18431
        int bb = gid / 2304;
        int r  = gid % 2304;
        const float* w0 = w + (long)bb * 1024;
        const float* w1 = w0 + 512;
        float acc = 0.f;
        if (r < 384) {
            for (int k = 0; k < 512; k++) acc += w0[k] * s1W[k * 384 + r];
            sout[bb * 384 + r] = acc + s1b[r];
        } else if (r < 768) {
            int c = r - 384;
            for (int k = 0; k < 512; k++) acc += w0[k] * s2W[k * 384 + c];
            sout[3072 + bb * 384 + c] = acc + s2b[c];
        } else {
            int c = r - 768;
            for (int k = 0; k < 512; k++) acc += w1[k] * ssW[k * 1536 + c];
            sout[6144 + bb * 1536 + c] = acc + ssb[c];
        }
    }
}

// ---------------- LayerNorm, one block per row of 768 ----------------
// MODE: 1 = bf16 only, 2 = f32 + bf16 dual output
template<int MODE>
__global__ __launch_bounds__(256) void ln_kernel(const float* __restrict__ x,
                                                 const float* __restrict__ g,
                                                 const float* __restrict__ b,
                                                 float* __restrict__ outf,
                                                 ushort* __restrict__ outb) {
    int row = blockIdx.x;
    const float* xr = x + (long)row * NC;
    int t = threadIdx.x;
    float v0 = xr[t], v1 = xr[t + 256], v2 = xr[t + 512];
    float s = v0 + v1 + v2;
    float s2 = v0 * v0 + v1 * v1 + v2 * v2;
    for (int off = 32; off > 0; off >>= 1) {
        s  += __shfl_down(s, off, 64);
        s2 += __shfl_down(s2, off, 64);
    }
    __shared__ float ls[4], ls2[4];
    int wid = t >> 6, lane = t & 63;
    if (lane == 0) { ls[wid] = s; ls2[wid] = s2; }
    __syncthreads();
    if (t == 0) {
        float ts = ls[0] + ls[1] + ls[2] + ls[3];
        float ts2 = ls2[0] + ls2[1] + ls2[2] + ls2[3];
        float mu = ts * (1.0f / NC);
        float var = ts2 * (1.0f / NC) - mu * mu;
        ls[0] = mu;
        ls2[0] = 1.0f / sqrtf(var + 1e-6f);
    }
    __syncthreads();
    float mu = ls[0], r = ls2[0];
#pragma unroll
    for (int i = 0; i < 3; i++) {
        int c = t + i * 256;
        float vv = (i == 0 ? v0 : (i == 1 ? v1 : v2));
        float o = (vv - mu) * r * g[c] + b[c];
        if (MODE == 2) outf[(long)row * NC + c] = o;
        outb[(long)row * NC + c] = f2b(o);
    }
}

extern "C" void kernel_launch(void* const* d_in, const int* in_sizes, int n_in,
                              void* d_out, int out_size, void* d_ws, size_t ws_size,
                              hipStream_t stream) {
    const float* x     = (const float*)d_in[0];
    const float* w     = (const float*)d_in[1];
    const float* ln1_g = (const float*)d_in[2];
    const float* ln1_b = (const float*)d_in[3];
    const float* ln2_g = (const float*)d_in[4];
    const float* ln2_b = (const float*)d_in[5];
    const float* g1_W  = (const float*)d_in[6];
    const float* g1_b  = (const float*)d_in[7];
    const float* s1_W  = (const float*)d_in[8];
    const float* s1_b  = (const float*)d_in[9];
    const float* m1_W  = (const float*)d_in[10];
    const float* m1_b  = (const float*)d_in[11];
    const float* g2_W  = (const float*)d_in[12];
    const float* g2_b  = (const float*)d_in[13];
    const float* s2_W  = (const float*)d_in[14];
    const float* s2_b  = (const float*)d_in[15];
    const float* m2_W  = (const float*)d_in[16];
    const float* m2_b  = (const float*)d_in[17];
    const float* gs_W  = (const float*)d_in[18];
    const float* gs_b  = (const float*)d_in[19];
    const float* ss_W  = (const float*)d_in[20];
    const float* ss_b  = (const float*)d_in[21];
    const float* ms_W  = (const float*)d_in[22];
    const float* ms_b  = (const float*)d_in[23];
    const float* r1_W  = (const float*)d_in[24];
    const float* r1_b  = (const float*)d_in[25];
    const float* r2_W  = (const float*)d_in[26];
    const float* r2_b  = (const float*)d_in[27];
    float* out = (float*)d_out;
    char* ws = (char*)d_ws;
    char* ob = (char*)d_out;

    // ---- ws layout (74,784,768 B; proven safe) ----
    float*  XLN = (float*)ws;                 // [16384,768] f32: xln -> x2 -> x3
    ushort* A1b = (ushort*)(ws + 50331648);   // 12.6 MB: a1 -> H1T -> AS chunks -> ar
    ushort* g1t = (ushort*)(ws + 62914560);   // W^T bf16 pool
    ushort* g2t = g1t + 589824;
    ushort* m1t = g2t + 589824;
    ushort* m2t = m1t + 147456;
    ushort* gst = m2t + 147456;
    ushort* mst = gst + 2359296;
    ushort* r1t = mst + 1179648;
    ushort* r2t = r1t + 589824;
    float*  SV  = (float*)(ws + 74711040);    // 18432 f32
    ushort* H1T = A1b;                        // [8,384,2048] alias
    ushort* ASq = A1b;                        // [4096,1536] chunk alias
    ushort* ARq = A1b;                        // [16384,384] alias

    // ---- d_out scratch phases ----
    ushort* XLNb  = (ushort*)(ob + 25165824); // p1a: [16384,768] bf16 xln (LN1 .. dual-GLU)
    ushort* XLNT  = (ushort*)(ob + 25165824); // p1b: [8,768,2048] bf16 (T1 .. mix) over XLNb
    ushort* A2q   = (ushort*)(ob + 12582912); // p1: a2 (dual-GLU .. h2)
    ushort* H2q   = (ushort*)ob;              // p1: h2 [16384,384] (h2 .. step8)
    ushort* H1q   = (ushort*)(ob + 12582912); // p1: h1 over a2 (h1 .. T2)
    float*  MIXTf = (float*)(ob + 12582912);  // p1: [8,768,384] f32 over h1 (mix)
    ushort* MIXTb = (ushort*)(ob + 25165824); // p1: bf16 over XLNT (gelu .. step8)
    ushort* X2LNq = (ushort*)(ob + 25165824); // p2: full ln2 [16384,768] bf16
    ushort* X3q   = (ushort*)ob;              // p2-3: x3 bf16 [16384,768]

    // 0. merged weight casts + style vectors; LN1 dual-output (f32 ws + bf16 XLNb)
    prep_kernel<<<23112, 256, 0, stream>>>(
        g1_W, g1t, g2_W, g2t, m1_W, m1t, m2_W, m2t, gs_W, gst, ms_W, mst,
        r1_W, r1t, r2_W, r2t, w, s1_W, s1_b, s2_W, s2_b, ss_W, ss_b, SV);
    ln_kernel<2><<<ROWS, 256, 0, stream>>>(x, ln1_g, ln1_b, XLN, XLNb);

    // 3+5. merged dual-GLU (all-DMA A from XLNb): a1 -> A1b, a2 -> A2q
    gemm_glu_mfma<128, true><<<dim3(3, 128, 2), 256, 0, stream>>>(
        XLNb, g1t, g2t, A1b, A2q, ROWS, 384, 768, 768, g1_b, g2_b, SV, SV + 3072, 0);
    // T1: XLNT = xln^T (reads f32 XLN in ws; overwrites dead XLNb)
    transpose_kernel<true><<<dim3(12, 32, NB), 256, 0, stream>>>(
        XLN, XLNT, 2048, 768, (long)2048 * 768, (long)768 * 2048);
    // 6. h2 = a2@m2 -> H2q
    gemm_mfma<64, 0, true, false><<<dim3(6, 128), 256, 0, stream>>>(
        A2q, m2t, nullptr, H2q, ROWS, 384, 384, 384, 384, 384, 0, 0, 0, m2_b);
    // 4. h1 = a1@m1 -> H1q (over dead a2)
    gemm_mfma<64, 0, true, false><<<dim3(6, 128), 256, 0, stream>>>(
        A1b, m1t, nullptr, H1q, ROWS, 384, 384, 384, 384, 384, 0, 0, 0, m1_b);
    // T2: H1T = h1^T -> A1b (a1 dead)
    transpose_kernel<false><<<dim3(6, 32, NB), 256, 0, stream>>>(
        H1q, H1T, 2048, 384, (long)2048 * 384, (long)384 * 2048);
    // 7. mixT(f32) += xlnT@h1T, split-K x4, atomic
    hipMemsetAsync(MIXTf, 0, (size_t)NB * 768 * 384 * 4, stream);
    gemm_mfma<128, 6, false, true><<<dim3(3, 6, NB * 4), 256, 0, stream>>>(
        XLNT, H1T, MIXTf, nullptr, 768, 384, 2048, 2048, 2048, 384,
        (long)768 * 2048, (long)384 * 2048, (long)768 * 384, nullptr);
    // gelu + cast -> MIXTb (over dead XLNT)
    gelu_cast_kernel<<<2304, 256, 0, stream>>>(MIXTf, MIXTb);
    // 8. x2 = xln + h2@mixT^T (f32 in-place)
    gemm_mfma<128, 3, false, false><<<dim3(6, 16, NB), 256, 0, stream>>>(
        H2q, MIXTb, XLN, nullptr, 2048, 768, 384, 384, 384, 768,
        (long)2048 * 384, (long)768 * 384, (long)2048 * 768, nullptr);
    // 9. full LN2 -> X2LNq bf16
    ln_kernel<1><<<ROWS, 256, 0, stream>>>(XLN, ln2_g, ln2_b, nullptr, X2LNq);
    // 10-11. style branch, 4 chunks of 4096 rows (AS buffer = A1b, 12.6 MB)
    for (int ch = 0; ch < 4; ch++) {
        ushort* X2c = X2LNq + (long)ch * 4096 * 768;
        float*  XLNc = XLN + (long)ch * 4096 * 768;
        ushort* X3c = X3q + (long)ch * 4096 * 768;
        gemm_glu_mfma<128, true><<<dim3(12, 32), 256, 0, stream>>>(
            X2c, gst, gst, ASq, ASq, 4096, 1536, 768, 768, gs_b, gs_b,
            SV + 6144, SV + 6144, ch * 2);
        gemm_mfma<128, 4, true, false><<<dim3(6, 32), 256, 0, stream>>>(
            ASq, mst, XLNc, X3c, 4096, 768, 1536, 1536, 1536, 768, 0, 0, 0, ms_b);
    }
    // 12. ar = glu(x3@r1_W) -> ARq
    gemm_glu_mfma<64, false><<<dim3(6, 128), 256, 0, stream>>>(
        X3q, r1t, r1t, ARq, ARq, ROWS, 384, 768, 768, r1_b, r1_b, nullptr, nullptr, 0);
    // 13. out = ar@r2_W + r2_b (fp32 final, overwrites all d_out scratch)
    gemm_mfma<128, 5, true, false><<<dim3(6, 128), 256, 0, stream>>>(
        ARq, r2t, out, nullptr, ROWS, 768, 384, 384, 384, 768, 0, 0, 0, r2_b);
}

// Round 16
// 773.786 us; speedup vs baseline: 1.0189x; 1.0189x over previous
//
#include <hip/hip_runtime.h>
#include <hip/hip_bf16.h>
#include <math.h>

#define NB 8
#define NT 2048
#define NC 768
#define ROWS (NB*NT)   // 16384

typedef __attribute__((ext_vector_type(8))) short s8v;   // 8 bf16 (4 VGPRs)
typedef __attribute__((ext_vector_type(4))) float f4v;   // 4 fp32 acc

__device__ __forceinline__ unsigned short f2b(float f) {  // fp32->bf16 RNE
    unsigned u = __builtin_bit_cast(unsigned, f);
    return (unsigned short)((u + 0x7FFFu + ((u >> 16) & 1u)) >> 16);
}

// async global->LDS DMA, 16B per lane. LDS dest = wave-uniform base + lane*16.
__device__ __forceinline__ void gll16(const ushort* g, ushort* l) {
    __builtin_amdgcn_global_load_lds(
        (const __attribute__((address_space(1))) void*)g,
        (__attribute__((address_space(3))) void*)l, 16, 0, 0);
}

// counted vmcnt wait (T4): wait until <=N of this wave's VMEM ops remain.
template<int N> __device__ __forceinline__ void waitcnt_vm() {
    if constexpr (N == 3)      asm volatile("s_waitcnt vmcnt(3)" ::: "memory");
    else if constexpr (N == 4) asm volatile("s_waitcnt vmcnt(4)" ::: "memory");
    else if constexpr (N == 6) asm volatile("s_waitcnt vmcnt(6)" ::: "memory");
    else                       asm volatile("s_waitcnt vmcnt(0)" ::: "memory");
}
__device__ __forceinline__ void hw_barrier() {   // barrier + compiler mem fence
    asm volatile("s_barrier" ::: "memory");
}

// T1 XCD-aware block swizzle (verified R14: dual-GLU FETCH 75->34.5 MB).
// Bijective iff nwg%8==0 (all our grids).
__device__ __forceinline__ void xcd_swz(int& bx, int& by, int& bz) {
    int gx = gridDim.x, gy = gridDim.y;
    int nwg = gx * gy * (int)gridDim.z;
    int flat = bx + gx * (by + gy * bz);
    int cpx = nwg >> 3;
    int s = (flat & 7) * cpx + (flat >> 3);
    bx = s % gx; int rem = s / gx;
    by = rem % gy; bz = rem / gy;
}

// ---------------- MFMA GEMM: C = A@B^T-layout (+bias)(+resid) ----------------
// A bf16 [M,K]; B bf16 [N,K] outer-major. Tile 128xTN, 4 waves.
// Counted-vmcnt double-buffered K-loop (T3+T4, verified R12/R14/R15), hoisted
// addressing. Sync structure: stage -> vmcnt(LP) -> barrier -> mfma -> barrier.
// EPI: 0=bf16+bias; 3=f32 resid in-place; 4=resid f32->bf16 out; 5=f32+bias; 6=atomic f32
template<int TN, int EPI, bool HASBIAS, bool SPLITK>
__global__ __launch_bounds__(256) void gemm_mfma(
    const ushort* __restrict__ A, const ushort* __restrict__ Bt,
    float* __restrict__ Cf, ushort* __restrict__ Cb,
    int M, int N, int K, int lda, int ldb, int ldc,
    long sA, long sB, long sC, const float* __restrict__ bias)
{
    constexpr int WM = (TN == 128) ? 64 : 32;
    constexpr int TI = WM / 16;               // 4 or 2
    constexpr int BN = TN * 32;
    constexpr int CB = TN / 64;               // B chunks per wave
    constexpr int LP = 2 + CB;                // gll16 per wave per K-step
    int bx = blockIdx.x, by = blockIdx.y, bz = blockIdx.z;
    xcd_swz(bx, by, bz);
    int zz = bz;
    int z  = SPLITK ? (zz >> 2) : zz;
    int kb = SPLITK ? (zz & 3) * (K >> 2) : 0;
    int ke = SPLITK ? kb + (K >> 2) : K;
    const ushort* Az = A + (long)z * sA;
    const ushort* Bz = Bt + (long)z * sB;
    float*  Cfz = Cf ? Cf + (long)z * sC : nullptr;
    ushort* Cbz = Cb ? Cb + (long)z * sC : nullptr;

    int m0 = by * 128, n0 = bx * TN;
    __shared__ alignas(16) ushort Al[8192];        // 2 x 128x32
    __shared__ alignas(16) ushort Bl[2 * BN];
    int t = threadIdx.x;
    int lane = t & 63, w = t >> 6;
    int wm = (TN == 128) ? (w >> 1) * 64 : w * 32;
    int wn = (TN == 128) ? (w & 1) * 64 : 0;
    int fr = lane & 15, q = lane >> 4;

    // ---- hoisted per-lane staging pointers (advance +32/K-step) ----
    int rs = lane >> 2, cb = lane & 3;
    const ushort* srcA[2]; ushort* dstA[2];
    const ushort* srcB[CB]; ushort* dstB[CB];
#pragma unroll
    for (int i = 0; i < 2; i++) {
        int ii = w + 4 * i, row = ii * 16 + rs;
        int kc = (cb ^ ((row >> 1) & 3)) << 3;
        srcA[i] = Az + (long)(m0 + row) * lda + kb + kc;
        dstA[i] = Al + ii * 512;
    }
#pragma unroll
    for (int i = 0; i < CB; i++) {
        int ii = w + 4 * i, row = ii * 16 + rs;
        int kc = (cb ^ ((row >> 1) & 3)) << 3;
        srcB[i] = Bz + (long)(n0 + row) * ldb + kb + kc;
        dstB[i] = Bl + ii * 512;
    }
    auto stage_adv = [&](int b) {
#pragma unroll
        for (int i = 0; i < 2; i++) { gll16(srcA[i], dstA[i] + b * 4096); srcA[i] += 32; }
#pragma unroll
        for (int i = 0; i < CB; i++) { gll16(srcB[i], dstB[i] + b * BN); srcB[i] += 32; }
    };

    // ---- hoisted swizzled ds_read byte offsets ----
    int offA[TI], offB[4];
#pragma unroll
    for (int ti = 0; ti < TI; ti++) {
        int r = wm + ti * 16 + fr;
        offA[ti] = r * 32 + ((q ^ ((r >> 1) & 3)) << 3);
    }
#pragma unroll
    for (int tj = 0; tj < 4; tj++) {
        int r = wn + tj * 16 + fr;
        offB[tj] = r * 32 + ((q ^ ((r >> 1) & 3)) << 3);
    }

    f4v acc[TI][4];
#pragma unroll
    for (int i = 0; i < TI; i++)
#pragma unroll
        for (int j = 0; j < 4; j++) acc[i][j] = (f4v)(0.0f);

    auto frag_mfma = [&](const ushort* AB, const ushort* BB) {
        s8v af[TI], bf[4];
#pragma unroll
        for (int ti = 0; ti < TI; ti++) af[ti] = *(const s8v*)&AB[offA[ti]];
#pragma unroll
        for (int tj = 0; tj < 4; tj++) bf[tj] = *(const s8v*)&BB[offB[tj]];
#pragma unroll
        for (int ti = 0; ti < TI; ti++)
#pragma unroll
            for (int tj = 0; tj < 4; tj++)
                acc[ti][tj] = __builtin_amdgcn_mfma_f32_16x16x32_bf16(
                    af[ti], bf[tj], acc[ti][tj], 0, 0, 0);
    };

    int nt = (ke - kb) >> 5;
    stage_adv(0);
    int cur = 0;
    for (int it = 0; it + 1 < nt; ++it) {
        stage_adv(cur ^ 1);
        waitcnt_vm<LP>();          // tile it landed; tile it+1 stays in flight
        hw_barrier();
        frag_mfma(Al + cur * 4096, Bl + cur * BN);
        hw_barrier();              // WAR guard for buffer recycle
        cur ^= 1;
    }
    waitcnt_vm<0>();               // last tile's loads
    hw_barrier();
    frag_mfma(Al + cur * 4096, Bl + cur * BN);

    int cr0 = q * 4;  // C/D: col = lane&15, row = (lane>>4)*4 + reg
#pragma unroll
    for (int ti = 0; ti < TI; ti++) {
#pragma unroll
        for (int tj = 0; tj < 4; tj++) {
            int n = n0 + wn + tj * 16 + fr;
            float bv = HASBIAS ? bias[n] : 0.0f;
#pragma unroll
            for (int r = 0; r < 4; r++) {
                int m = m0 + wm + ti * 16 + cr0 + r;
                long idx = (long)m * ldc + n;
                float v = acc[ti][tj][r] + bv;
                if (EPI == 0) {
                    Cbz[idx] = f2b(v);
                } else if (EPI == 5) {
                    Cfz[idx] = v;
                } else if (EPI == 6) {
                    __hip_atomic_fetch_add(&Cfz[idx], v, __ATOMIC_RELAXED,
                                           __HIP_MEMORY_SCOPE_AGENT);
                } else {  // 3, 4
                    v += Cfz[idx];
                    if (EPI == 3) Cfz[idx] = v;      // x2 f32 (read by LN2 + style resid)
                    if (EPI == 4) Cbz[idx] = f2b(v); // x3 f32 copy is never read: skip store
                }
            }
        }
    }
}

// ---------------- fused GLU GEMM: out = (A@Wv+bv)*sigmoid(A@Wg+bg)*s ----------------
// A bf16 (DMA-staged). B = W^T bf16 [2Nh, K]. grid.z selects pair.
// Same hoisted-addressing counted-vmcnt schedule as gemm_mfma.
template<int TN, bool HAS_S>
__global__ __launch_bounds__(256) void gemm_glu_mfma(
    const ushort* __restrict__ A,
    const ushort* __restrict__ Bt0, const ushort* __restrict__ Bt1,
    ushort* __restrict__ C0, ushort* __restrict__ C1,
    int M, int Nh, int K, int lda,
    const float* __restrict__ bias0, const float* __restrict__ bias1,
    const float* __restrict__ s0, const float* __restrict__ s1, int bofs)
{
    constexpr int WM = (TN == 128) ? 64 : 32;
    constexpr int TI = WM / 16;
    constexpr int BN = TN * 32;
    constexpr int CB = TN / 64;
    constexpr int LP = 2 + 2 * CB;            // gll16 per wave per K-step
    int bx = blockIdx.x, by = blockIdx.y, bz = blockIdx.z;
    xcd_swz(bx, by, bz);
    int z = bz;
    const ushort* Bt = z ? Bt1 : Bt0;
    ushort* Cb = z ? C1 : C0;
    const float* bias = z ? bias1 : bias0;
    const float* s = z ? s1 : s0;

    int m0 = by * 128, n0 = bx * TN;
    __shared__ alignas(16) ushort Al[8192];
    __shared__ alignas(16) ushort B1[2 * BN];
    __shared__ alignas(16) ushort B2[2 * BN];
    int t = threadIdx.x;
    int lane = t & 63, w = t >> 6;
    int wm = (TN == 128) ? (w >> 1) * 64 : w * 32;
    int wn = (TN == 128) ? (w & 1) * 64 : 0;
    int fr = lane & 15, q = lane >> 4;

    // ---- hoisted per-lane staging pointers ----
    int rs = lane >> 2, cbn = lane & 3;
    const ushort* srcA[2]; ushort* dstA[2];
    const ushort* srcU[CB]; ushort* dstU[CB];
    const ushort* srcV[CB]; ushort* dstV[CB];
#pragma unroll
    for (int i = 0; i < 2; i++) {
        int ii = w + 4 * i, row = ii * 16 + rs;
        int kc = (cbn ^ ((row >> 1) & 3)) << 3;
        srcA[i] = A + (long)(m0 + row) * lda + kc;
        dstA[i] = Al + ii * 512;
    }
#pragma unroll
    for (int i = 0; i < CB; i++) {
        int ii = w + 4 * i, row = ii * 16 + rs;
        int kc = (cbn ^ ((row >> 1) & 3)) << 3;
        srcU[i] = Bt + (long)(n0 + row) * K + kc;
        srcV[i] = Bt + (long)(Nh + n0 + row) * K + kc;
        dstU[i] = B1 + ii * 512;
        dstV[i] = B2 + ii * 512;
    }
    auto stage_adv = [&](int b) {
#pragma unroll
        for (int i = 0; i < CB; i++) { gll16(srcU[i], dstU[i] + b * BN); srcU[i] += 32; }
#pragma unroll
        for (int i = 0; i < CB; i++) { gll16(srcV[i], dstV[i] + b * BN); srcV[i] += 32; }
#pragma unroll
        for (int i = 0; i < 2; i++)  { gll16(srcA[i], dstA[i] + b * 4096); srcA[i] += 32; }
    };

    // ---- hoisted swizzled ds_read byte offsets ----
    int offA[TI], offB[4];
#pragma unroll
    for (int ti = 0; ti < TI; ti++) {
        int r = wm + ti * 16 + fr;
        offA[ti] = r * 32 + ((q ^ ((r >> 1) & 3)) << 3);
    }
#pragma unroll
    for (int tj = 0; tj < 4; tj++) {
        int r = wn + tj * 16 + fr;
        offB[tj] = r * 32 + ((q ^ ((r >> 1) & 3)) << 3);
    }

    f4v acc1[TI][4], acc2[TI][4];
#pragma unroll
    for (int i = 0; i < TI; i++)
#pragma unroll
        for (int j = 0; j < 4; j++) { acc1[i][j] = (f4v)(0.0f); acc2[i][j] = (f4v)(0.0f); }

    auto frag_mfma = [&](const ushort* AB, const ushort* BB1, const ushort* BB2) {
        s8v af[TI], b1f[4], b2f[4];
#pragma unroll
        for (int ti = 0; ti < TI; ti++) af[ti] = *(const s8v*)&AB[offA[ti]];
#pragma unroll
        for (int tj = 0; tj < 4; tj++) {
            b1f[tj] = *(const s8v*)&BB1[offB[tj]];
            b2f[tj] = *(const s8v*)&BB2[offB[tj]];
        }
#pragma unroll
        for (int ti = 0; ti < TI; ti++)
#pragma unroll
            for (int tj = 0; tj < 4; tj++) {
                acc1[ti][tj] = __builtin_amdgcn_mfma_f32_16x16x32_bf16(af[ti], b1f[tj], acc1[ti][tj], 0, 0, 0);
                acc2[ti][tj] = __builtin_amdgcn_mfma_f32_16x16x32_bf16(af[ti], b2f[tj], acc2[ti][tj], 0, 0, 0);
            }
    };

    int nt = K >> 5;
    stage_adv(0);
    int cur = 0;
    for (int it = 0; it + 1 < nt; ++it) {
        stage_adv(cur ^ 1);
        waitcnt_vm<LP>();          // tile it landed; tile it+1 stays in flight
        hw_barrier();
        frag_mfma(Al + cur * 4096, B1 + cur * BN, B2 + cur * BN);
        hw_barrier();              // WAR guard for buffer recycle
        cur ^= 1;
    }
    waitcnt_vm<0>();
    hw_barrier();
    frag_mfma(Al + cur * 4096, B1 + cur * BN, B2 + cur * BN);

    int cr0 = q * 4;
#pragma unroll
    for (int ti = 0; ti < TI; ti++) {
        int bb = ((m0 + wm + ti * 16 + cr0) >> 11) + bofs;   // batch = row/2048
#pragma unroll
        for (int tj = 0; tj < 4; tj++) {
            int n = n0 + wn + tj * 16 + fr;
            float bv = bias[n], bg = bias[Nh + n];
            float sv = HAS_S ? s[(long)bb * Nh + n] : 1.0f;
#pragma unroll
            for (int r = 0; r < 4; r++) {
                int m = m0 + wm + ti * 16 + cr0 + r;
                float vv = acc1[ti][tj][r] + bv;
                float gg = acc2[ti][tj][r] + bg;
                float a = vv * (1.0f / (1.0f + __expf(-gg)));
                if (HAS_S) a *= sv;
                Cb[(long)m * Nh + n] = f2b(a);
            }
        }
    }
}

// ---------------- gelu + cast fp32 -> bf16 (elementwise, float4) ----------------
__global__ __launch_bounds__(256) void gelu_cast_kernel(const float* __restrict__ in,
                                                        ushort* __restrict__ out) {
    int i4 = (blockIdx.x * 256 + threadIdx.x) * 4;
    float4 v = *(const float4*)(in + i4);
    ushort4 o;
    o.x = f2b(0.5f * v.x * (1.0f + erff(v.x * 0.70710678118654752440f)));
    o.y = f2b(0.5f * v.y * (1.0f + erff(v.y * 0.70710678118654752440f)));
    o.z = f2b(0.5f * v.z * (1.0f + erff(v.z * 0.70710678118654752440f)));
    o.w = f2b(0.5f * v.w * (1.0f + erff(v.w * 0.70710678118654752440f)));
    *(ushort4*)(out + i4) = o;
}

// ---------------- transpose: src [R,C] (batched) -> dst bf16 [C,R] ----------------
template<bool SRC_F32>
__global__ __launch_bounds__(256) void transpose_kernel(const void* __restrict__ src,
                                                        ushort* __restrict__ dst,
                                                        int R, int C, long sS, long sD) {
    int z = blockIdx.z;
    const void* S = SRC_F32 ? (const void*)((const float*)src + (long)z * sS)
                            : (const void*)((const ushort*)src + (long)z * sS);
    ushort* D = dst + (long)z * sD;
    int r0 = blockIdx.y * 64, c0 = blockIdx.x * 64;
    __shared__ ushort T[64][68];
    int t = threadIdx.x;
#pragma unroll
    for (int p = 0; p < 4; p++) {
        int e = p * 256 + t;
        int row = e >> 4, cc = (e & 15) * 4;
        ushort4 v;
        if (SRC_F32) {
            float4 f = *(const float4*)((const float*)S + (long)(r0 + row) * C + c0 + cc);
            v.x = f2b(f.x); v.y = f2b(f.y); v.z = f2b(f.z); v.w = f2b(f.w);
        } else {
            v = *(const ushort4*)((const ushort*)S + (long)(r0 + row) * C + c0 + cc);
        }
        *(ushort4*)&T[row][cc] = v;
    }
    __syncthreads();
#pragma unroll
    for (int p = 0; p < 4; p++) {
        int e = p * 256 + t;
        int crow = e >> 4, rr = (e & 15) * 4;
        ushort4 o;
        o.x = T[rr + 0][crow]; o.y = T[rr + 1][crow];
        o.z = T[rr + 2][crow]; o.w = T[rr + 3][crow];
        *(ushort4*)&D[(long)(c0 + crow) * R + r0 + rr] = o;
    }
}

// ---------------- merged prep: 8 weight casts + style vectors + LN1 ----------------
// blocks [0,23040): castT; [23040,23112): svec; [23112,39496): LN1 rows
// (independent work fused to overlap HBM streams and drop a launch gap).
__global__ __launch_bounds__(256) void prep_kernel(
    const float* __restrict__ g1_W, ushort* __restrict__ g1t,
    const float* __restrict__ g2_W, ushort* __restrict__ g2t,
    const float* __restrict__ m1_W, ushort* __restrict__ m1t,
    const float* __restrict__ m2_W, ushort* __restrict__ m2t,
    const float* __restrict__ gs_W, ushort* __restrict__ gst,
    const float* __restrict__ ms_W, ushort* __restrict__ mst,
    const float* __restrict__ r1_W, ushort* __restrict__ r1t,
    const float* __restrict__ r2_W, ushort* __restrict__ r2t,
    const float* __restrict__ w,
    const float* __restrict__ s1W, const float* __restrict__ s1b,
    const float* __restrict__ s2W, const float* __restrict__ s2b,
    const float* __restrict__ ssW, const float* __restrict__ ssb,
    float* __restrict__ sout,
    const float* __restrict__ x,
    const float* __restrict__ ln1_g, const float* __restrict__ ln1_b,
    float* __restrict__ xlnf, ushort* __restrict__ xlnb)
{
    int b = blockIdx.x, t = threadIdx.x;
    if (b < 23040) {
        const float* W; ushort* Wt; int K, N, lo;
        if      (b < 2304)  { W = g1_W; Wt = g1t; K = 768;  N = 768;  lo = 0; }
        else if (b < 4608)  { W = g2_W; Wt = g2t; K = 768;  N = 768;  lo = 2304; }
        else if (b < 5184)  { W = m1_W; Wt = m1t; K = 384;  N = 384;  lo = 4608; }
        else if (b < 5760)  { W = m2_W; Wt = m2t; K = 384;  N = 384;  lo = 5184; }
        else if (b < 14976) { W = gs_W; Wt = gst; K = 768;  N = 3072; lo = 5760; }
        else if (b < 19584) { W = ms_W; Wt = mst; K = 1536; N = 768;  lo = 14976; }
        else if (b < 21888) { W = r1_W; Wt = r1t; K = 768;  N = 768;  lo = 19584; }
        else                { W = r2_W; Wt = r2t; K = 384;  N = 768;  lo = 21888; }
        int local = b - lo, bx = K >> 6;
        int byi = local / bx, bxi = local - byi * bx;
        int k = bxi * 64 + (t & 63), n = byi * 4 + (t >> 6);
        Wt[(long)n * K + k] = f2b(W[(long)k * N + n]);
    } else if (b < 23112) {
        int gid = (b - 23040) * 256 + t;   // 0..18431
        int bb = gid / 2304;
        int r  = gid % 2304;
        const float* w0 = w + (long)bb * 1024;
        const float* w1 = w0 + 512;
        float acc = 0.f;
        if (r < 384) {
            for (int k = 0; k < 512; k++) acc += w0[k] * s1W[k * 384 + r];
            sout[bb * 384 + r] = acc + s1b[r];
        } else if (r < 768) {
            int c = r - 384;
            for (int k = 0; k < 512; k++) acc += w0[k] * s2W[k * 384 + c];
            sout[3072 + bb * 384 + c] = acc + s2b[c];
        } else {
            int c = r - 768;
            for (int k = 0; k < 512; k++) acc += w1[k] * ssW[k * 1536 + c];
            sout[6144 + bb * 1536 + c] = acc + ssb[c];
        }
    } else {
        // LN1 (dual output f32 + bf16), row = b - 23112
        int row = b - 23112;
        const float* xr = x + (long)row * NC;
        float v0 = xr[t], v1 = xr[t + 256], v2 = xr[t + 512];
        float s = v0 + v1 + v2;
        float s2 = v0 * v0 + v1 * v1 + v2 * v2;
        for (int off = 32; off > 0; off >>= 1) {
            s  += __shfl_down(s, off, 64);
            s2 += __shfl_down(s2, off, 64);
        }
        __shared__ float ls[4], ls2[4];
        int wid = t >> 6, lane = t & 63;
        if (lane == 0) { ls[wid] = s; ls2[wid] = s2; }
        __syncthreads();
        if (t == 0) {
            float ts = ls[0] + ls[1] + ls[2] + ls[3];
            float ts2 = ls2[0] + ls2[1] + ls2[2] + ls2[3];
            float mu = ts * (1.0f / NC);
            float var = ts2 * (1.0f / NC) - mu * mu;
            ls[0] = mu;
            ls2[0] = 1.0f / sqrtf(var + 1e-6f);
        }
        __syncthreads();
        float mu = ls[0], r = ls2[0];
#pragma unroll
        for (int i = 0; i < 3; i++) {
            int c = t + i * 256;
            float vv = (i == 0 ? v0 : (i == 1 ? v1 : v2));
            float o = (vv - mu) * r * ln1_g[c] + ln1_b[c];
            xlnf[(long)row * NC + c] = o;
            xlnb[(long)row * NC + c] = f2b(o);
        }
    }
}

// ---------------- LayerNorm (LN2), one block per row of 768; bf16 out ----------------
__global__ __launch_bounds__(256) void ln_kernel(const float* __restrict__ x,
                                                 const float* __restrict__ g,
                                                 const float* __restrict__ b,
                                                 ushort* __restrict__ outb) {
    int row = blockIdx.x;
    const float* xr = x + (long)row * NC;
    int t = threadIdx.x;
    float v0 = xr[t], v1 = xr[t + 256], v2 = xr[t + 512];
    float s = v0 + v1 + v2;
    float s2 = v0 * v0 + v1 * v1 + v2 * v2;
    for (int off = 32; off > 0; off >>= 1) {
        s  += __shfl_down(s, off, 64);
        s2 += __shfl_down(s2, off, 64);
    }
    __shared__ float ls[4], ls2[4];
    int wid = t >> 6, lane = t & 63;
    if (lane == 0) { ls[wid] = s; ls2[wid] = s2; }
    __syncthreads();
    if (t == 0) {
        float ts = ls[0] + ls[1] + ls[2] + ls[3];
        float ts2 = ls2[0] + ls2[1] + ls2[2] + ls2[3];
        float mu = ts * (1.0f / NC);
        float var = ts2 * (1.0f / NC) - mu * mu;
        ls[0] = mu;
        ls2[0] = 1.0f / sqrtf(var + 1e-6f);
    }
    __syncthreads();
    float mu = ls[0], r = ls2[0];
#pragma unroll
    for (int i = 0; i < 3; i++) {
        int c = t + i * 256;
        float vv = (i == 0 ? v0 : (i == 1 ? v1 : v2));
        float o = (vv - mu) * r * g[c] + b[c];
        outb[(long)row * NC + c] = f2b(o);
    }
}

extern "C" void kernel_launch(void* const* d_in, const int* in_sizes, int n_in,
                              void* d_out, int out_size, void* d_ws, size_t ws_size,
                              hipStream_t stream) {
    const float* x     = (const float*)d_in[0];
    const float* w     = (const float*)d_in[1];
    const float* ln1_g = (const float*)d_in[2];
    const float* ln1_b = (const float*)d_in[3];
    const float* ln2_g = (const float*)d_in[4];
    const float* ln2_b = (const float*)d_in[5];
    const float* g1_W  = (const float*)d_in[6];
    const float* g1_b  = (const float*)d_in[7];
    const float* s1_W  = (const float*)d_in[8];
    const float* s1_b  = (const float*)d_in[9];
    const float* m1_W  = (const float*)d_in[10];
    const float* m1_b  = (const float*)d_in[11];
    const float* g2_W  = (const float*)d_in[12];
    const float* g2_b  = (const float*)d_in[13];
    const float* s2_W  = (const float*)d_in[14];
    const float* s2_b  = (const float*)d_in[15];
    const float* m2_W  = (const float*)d_in[16];
    const float* m2_b  = (const float*)d_in[17];
    const float* gs_W  = (const float*)d_in[18];
    const float* gs_b  = (const float*)d_in[19];
    const float* ss_W  = (const float*)d_in[20];
    const float* ss_b  = (const float*)d_in[21];
    const float* ms_W  = (const float*)d_in[22];
    const float* ms_b  = (const float*)d_in[23];
    const float* r1_W  = (const float*)d_in[24];
    const float* r1_b  = (const float*)d_in[25];
    const float* r2_W  = (const float*)d_in[26];
    const float* r2_b  = (const float*)d_in[27];
    float* out = (float*)d_out;
    char* ws = (char*)d_ws;
    char* ob = (char*)d_out;

    // ---- ws layout (74,784,768 B; proven safe) ----
    float*  XLN = (float*)ws;                 // [16384,768] f32: xln -> x2 -> x3
    ushort* A1b = (ushort*)(ws + 50331648);   // 12.6 MB: a1 -> H1T -> AS chunks -> ar
    ushort* g1t = (ushort*)(ws + 62914560);   // W^T bf16 pool
    ushort* g2t = g1t + 589824;
    ushort* m1t = g2t + 589824;
    ushort* m2t = m1t + 147456;
    ushort* gst = m2t + 147456;
    ushort* mst = gst + 2359296;
    ushort* r1t = mst + 1179648;
    ushort* r2t = r1t + 589824;
    float*  SV  = (float*)(ws + 74711040);    // 18432 f32
    ushort* H1T = A1b;                        // [8,384,2048] alias
    ushort* ASq = A1b;                        // [4096,1536] chunk alias
    ushort* ARq = A1b;                        // [16384,384] alias

    // ---- d_out scratch phases ----
    ushort* XLNb  = (ushort*)(ob + 25165824); // p1a: [16384,768] bf16 xln (LN1 .. dual-GLU)
    ushort* XLNT  = (ushort*)(ob + 25165824); // p1b: [8,768,2048] bf16 (T1 .. mix) over XLNb
    ushort* A2q   = (ushort*)(ob + 12582912); // p1: a2 (dual-GLU .. h2)
    ushort* H2q   = (ushort*)ob;              // p1: h2 [16384,384] (h2 .. step8)
    ushort* H1q   = (ushort*)(ob + 12582912); // p1: h1 over a2 (h1 .. T2)
    float*  MIXTf = (float*)(ob + 12582912);  // p1: [8,768,384] f32 over h1 (mix)
    ushort* MIXTb = (ushort*)(ob + 25165824); // p1: bf16 over XLNT (gelu .. step8)
    ushort* X2LNq = (ushort*)(ob + 25165824); // p2: full ln2 [16384,768] bf16
    ushort* X3q   = (ushort*)ob;              // p2-3: x3 bf16 [16384,768]

    // 0. merged weight casts + style vectors + LN1 (dual out) in ONE dispatch
    prep_kernel<<<39496, 256, 0, stream>>>(
        g1_W, g1t, g2_W, g2t, m1_W, m1t, m2_W, m2t, gs_W, gst, ms_W, mst,
        r1_W, r1t, r2_W, r2t, w, s1_W, s1_b, s2_W, s2_b, ss_W, ss_b, SV,
        x, ln1_g, ln1_b, XLN, XLNb);

    // 3+5. merged dual-GLU (all-DMA A from XLNb): a1 -> A1b, a2 -> A2q
    gemm_glu_mfma<128, true><<<dim3(3, 128, 2), 256, 0, stream>>>(
        XLNb, g1t, g2t, A1b, A2q, ROWS, 384, 768, 768, g1_b, g2_b, SV, SV + 3072, 0);
    // T1: XLNT = xln^T (reads f32 XLN in ws; overwrites dead XLNb)
    transpose_kernel<true><<<dim3(12, 32, NB), 256, 0, stream>>>(
        XLN, XLNT, 2048, 768, (long)2048 * 768, (long)768 * 2048);
    // 6. h2 = a2@m2 -> H2q
    gemm_mfma<64, 0, true, false><<<dim3(6, 128), 256, 0, stream>>>(
        A2q, m2t, nullptr, H2q, ROWS, 384, 384, 384, 384, 384, 0, 0, 0, m2_b);
    // 4. h1 = a1@m1 -> H1q (over dead a2)
    gemm_mfma<64, 0, true, false><<<dim3(6, 128), 256, 0, stream>>>(
        A1b, m1t, nullptr, H1q, ROWS, 384, 384, 384, 384, 384, 0, 0, 0, m1_b);
    // T2: H1T = h1^T -> A1b (a1 dead)
    transpose_kernel<false><<<dim3(6, 32, NB), 256, 0, stream>>>(
        H1q, H1T, 2048, 384, (long)2048 * 384, (long)384 * 2048);
    // 7. mixT(f32) += xlnT@h1T, split-K x4, atomic
    hipMemsetAsync(MIXTf, 0, (size_t)NB * 768 * 384 * 4, stream);
    gemm_mfma<128, 6, false, true><<<dim3(3, 6, NB * 4), 256, 0, stream>>>(
        XLNT, H1T, MIXTf, nullptr, 768, 384, 2048, 2048, 2048, 384,
        (long)768 * 2048, (long)384 * 2048, (long)768 * 384, nullptr);
    // gelu + cast -> MIXTb (over dead XLNT)
    gelu_cast_kernel<<<2304, 256, 0, stream>>>(MIXTf, MIXTb);
    // 8. x2 = xln + h2@mixT^T (f32 in-place)
    gemm_mfma<128, 3, false, false><<<dim3(6, 16, NB), 256, 0, stream>>>(
        H2q, MIXTb, XLN, nullptr, 2048, 768, 384, 384, 384, 768,
        (long)2048 * 384, (long)768 * 384, (long)2048 * 768, nullptr);
    // 9. full LN2 -> X2LNq bf16
    ln_kernel<<<ROWS, 256, 0, stream>>>(XLN, ln2_g, ln2_b, X2LNq);
    // 10-11. style branch, 4 chunks of 4096 rows (AS buffer = A1b, 12.6 MB)
    for (int ch = 0; ch < 4; ch++) {
        ushort* X2c = X2LNq + (long)ch * 4096 * 768;
        float*  XLNc = XLN + (long)ch * 4096 * 768;
        ushort* X3c = X3q + (long)ch * 4096 * 768;
        gemm_glu_mfma<128, true><<<dim3(12, 32), 256, 0, stream>>>(
            X2c, gst, gst, ASq, ASq, 4096, 1536, 768, 768, gs_b, gs_b,
            SV + 6144, SV + 6144, ch * 2);
        gemm_mfma<128, 4, true, false><<<dim3(6, 32), 256, 0, stream>>>(
            ASq, mst, XLNc, X3c, 4096, 768, 1536, 1536, 1536, 768, 0, 0, 0, ms_b);
    }
    // 12. ar = glu(x3@r1_W) -> ARq
    gemm_glu_mfma<64, false><<<dim3(6, 128), 256, 0, stream>>>(
        X3q, r1t, r1t, ARq, ARq, ROWS, 384, 768, 768, r1_b, r1_b, nullptr, nullptr, 0);
    // 13. out = ar@r2_W + r2_b (fp32 final, overwrites all d_out scratch)
    gemm_mfma<128, 5, true, false><<<dim3(6, 128), 256, 0, stream>>>(
        ARq, r2t, out, nullptr, ROWS, 768, 384, 384, 384, 768, 0, 0, 0, r2_b);
}

// Round 18
// 767.926 us; speedup vs baseline: 1.0267x; 1.0076x over previous
//
#include <hip/hip_runtime.h>
#include <hip/hip_bf16.h>
#include <math.h>

#define NB 8
#define NT 2048
#define NC 768
#define ROWS (NB*NT)   // 16384

typedef __attribute__((ext_vector_type(8))) short s8v;   // 8 bf16 (4 VGPRs)
typedef __attribute__((ext_vector_type(4))) float f4v;   // 4 fp32 acc

__device__ __forceinline__ unsigned short f2b(float f) {  // fp32->bf16 RNE
    unsigned u = __builtin_bit_cast(unsigned, f);
    return (unsigned short)((u + 0x7FFFu + ((u >> 16) & 1u)) >> 16);
}

// async global->LDS DMA, 16B per lane. LDS dest = wave-uniform base + lane*16.
__device__ __forceinline__ void gll16(const ushort* g, ushort* l) {
    __builtin_amdgcn_global_load_lds(
        (const __attribute__((address_space(1))) void*)g,
        (__attribute__((address_space(3))) void*)l, 16, 0, 0);
}

// counted vmcnt wait (T4): wait until <=N of this wave's VMEM ops remain.
template<int N> __device__ __forceinline__ void waitcnt_vm() {
    if constexpr (N == 3)      asm volatile("s_waitcnt vmcnt(3)" ::: "memory");
    else if constexpr (N == 4) asm volatile("s_waitcnt vmcnt(4)" ::: "memory");
    else if constexpr (N == 6) asm volatile("s_waitcnt vmcnt(6)" ::: "memory");
    else                       asm volatile("s_waitcnt vmcnt(0)" ::: "memory");
}
__device__ __forceinline__ void hw_barrier() {   // barrier + compiler mem fence
    asm volatile("s_barrier" ::: "memory");
}

// T1 XCD-aware block swizzle (verified R14: dual-GLU FETCH 75->34.5 MB).
// Bijective iff nwg%8==0 (all our grids).
__device__ __forceinline__ void xcd_swz(int& bx, int& by, int& bz) {
    int gx = gridDim.x, gy = gridDim.y;
    int nwg = gx * gy * (int)gridDim.z;
    int flat = bx + gx * (by + gy * bz);
    int cpx = nwg >> 3;
    int s = (flat & 7) * cpx + (flat >> 3);
    bx = s % gx; int rem = s / gx;
    by = rem % gy; bz = rem / gy;
}

// ---------------- MFMA GEMM: C = A@B^T-layout (+bias)(+resid) ----------------
// A bf16 [M,K]; B bf16 [N,K] outer-major. Tile 128xTN, 4 waves.
// Counted-vmcnt double-buffered K-loop (T3+T4, verified R12/R14/R15), hoisted
// addressing. Sync structure: stage -> vmcnt(LP) -> barrier -> mfma -> barrier.
// EPI: 0=bf16+bias; 3=f32 resid in-place; 4=resid f32->bf16 out; 5=f32+bias;
//      6=atomic f32; 7=TRANSPOSED bf16 store Cb[batch][n][m%2048] (fuses T2)
template<int TN, int EPI, bool HASBIAS, bool SPLITK>
__global__ __launch_bounds__(256) void gemm_mfma(
    const ushort* __restrict__ A, const ushort* __restrict__ Bt,
    float* __restrict__ Cf, ushort* __restrict__ Cb,
    int M, int N, int K, int lda, int ldb, int ldc,
    long sA, long sB, long sC, const float* __restrict__ bias)
{
    constexpr int WM = (TN == 128) ? 64 : 32;
    constexpr int TI = WM / 16;               // 4 or 2
    constexpr int BN = TN * 32;
    constexpr int CB = TN / 64;               // B chunks per wave
    constexpr int LP = 2 + CB;                // gll16 per wave per K-step
    int bx = blockIdx.x, by = blockIdx.y, bz = blockIdx.z;
    xcd_swz(bx, by, bz);
    int zz = bz;
    int z  = SPLITK ? (zz >> 2) : zz;
    int kb = SPLITK ? (zz & 3) * (K >> 2) : 0;
    int ke = SPLITK ? kb + (K >> 2) : K;
    const ushort* Az = A + (long)z * sA;
    const ushort* Bz = Bt + (long)z * sB;
    float*  Cfz = Cf ? Cf + (long)z * sC : nullptr;
    ushort* Cbz = Cb ? Cb + (long)z * sC : nullptr;

    int m0 = by * 128, n0 = bx * TN;
    __shared__ alignas(16) ushort Al[8192];        // 2 x 128x32
    __shared__ alignas(16) ushort Bl[2 * BN];
    int t = threadIdx.x;
    int lane = t & 63, w = t >> 6;
    int wm = (TN == 128) ? (w >> 1) * 64 : w * 32;
    int wn = (TN == 128) ? (w & 1) * 64 : 0;
    int fr = lane & 15, q = lane >> 4;

    // ---- hoisted per-lane staging pointers (advance +32/K-step) ----
    int rs = lane >> 2, cb = lane & 3;
    const ushort* srcA[2]; ushort* dstA[2];
    const ushort* srcB[CB]; ushort* dstB[CB];
#pragma unroll
    for (int i = 0; i < 2; i++) {
        int ii = w + 4 * i, row = ii * 16 + rs;
        int kc = (cb ^ ((row >> 1) & 3)) << 3;
        srcA[i] = Az + (long)(m0 + row) * lda + kb + kc;
        dstA[i] = Al + ii * 512;
    }
#pragma unroll
    for (int i = 0; i < CB; i++) {
        int ii = w + 4 * i, row = ii * 16 + rs;
        int kc = (cb ^ ((row >> 1) & 3)) << 3;
        srcB[i] = Bz + (long)(n0 + row) * ldb + kb + kc;
        dstB[i] = Bl + ii * 512;
    }
    auto stage_adv = [&](int b) {
#pragma unroll
        for (int i = 0; i < 2; i++) { gll16(srcA[i], dstA[i] + b * 4096); srcA[i] += 32; }
#pragma unroll
        for (int i = 0; i < CB; i++) { gll16(srcB[i], dstB[i] + b * BN); srcB[i] += 32; }
    };

    // ---- hoisted swizzled ds_read byte offsets ----
    int offA[TI], offB[4];
#pragma unroll
    for (int ti = 0; ti < TI; ti++) {
        int r = wm + ti * 16 + fr;
        offA[ti] = r * 32 + ((q ^ ((r >> 1) & 3)) << 3);
    }
#pragma unroll
    for (int tj = 0; tj < 4; tj++) {
        int r = wn + tj * 16 + fr;
        offB[tj] = r * 32 + ((q ^ ((r >> 1) & 3)) << 3);
    }

    f4v acc[TI][4];
#pragma unroll
    for (int i = 0; i < TI; i++)
#pragma unroll
        for (int j = 0; j < 4; j++) acc[i][j] = (f4v)(0.0f);

    auto frag_mfma = [&](const ushort* AB, const ushort* BB) {
        s8v af[TI], bf[4];
#pragma unroll
        for (int ti = 0; ti < TI; ti++) af[ti] = *(const s8v*)&AB[offA[ti]];
#pragma unroll
        for (int tj = 0; tj < 4; tj++) bf[tj] = *(const s8v*)&BB[offB[tj]];
#pragma unroll
        for (int ti = 0; ti < TI; ti++)
#pragma unroll
            for (int tj = 0; tj < 4; tj++)
                acc[ti][tj] = __builtin_amdgcn_mfma_f32_16x16x32_bf16(
                    af[ti], bf[tj], acc[ti][tj], 0, 0, 0);
    };

    int nt = (ke - kb) >> 5;
    stage_adv(0);
    int cur = 0;
    for (int it = 0; it + 1 < nt; ++it) {
        stage_adv(cur ^ 1);
        waitcnt_vm<LP>();          // tile it landed; tile it+1 stays in flight
        hw_barrier();
        frag_mfma(Al + cur * 4096, Bl + cur * BN);
        hw_barrier();              // WAR guard for buffer recycle
        cur ^= 1;
    }
    waitcnt_vm<0>();               // last tile's loads
    hw_barrier();
    frag_mfma(Al + cur * 4096, Bl + cur * BN);

    int cr0 = q * 4;  // C/D: col = lane&15, row = (lane>>4)*4 + reg
#pragma unroll
    for (int ti = 0; ti < TI; ti++) {
#pragma unroll
        for (int tj = 0; tj < 4; tj++) {
            int n = n0 + wn + tj * 16 + fr;
            float bv = HASBIAS ? bias[n] : 0.0f;
            if (EPI == 7) {
                // transposed store: H1T[batch][n][m&2047], 8B-aligned ushort4
                int mb = m0 + wm + ti * 16 + cr0;          // r=0 row
                ushort4 o;
                o.x = f2b(acc[ti][tj][0] + bv);
                o.y = f2b(acc[ti][tj][1] + bv);
                o.z = f2b(acc[ti][tj][2] + bv);
                o.w = f2b(acc[ti][tj][3] + bv);
                long idxT = ((long)(mb >> 11) * N + n) * 2048 + (mb & 2047);
                *(ushort4*)&Cbz[idxT] = o;
                continue;
            }
#pragma unroll
            for (int r = 0; r < 4; r++) {
                int m = m0 + wm + ti * 16 + cr0 + r;
                long idx = (long)m * ldc + n;
                float v = acc[ti][tj][r] + bv;
                if (EPI == 0) {
                    Cbz[idx] = f2b(v);
                } else if (EPI == 5) {
                    Cfz[idx] = v;
                } else if (EPI == 6) {
                    __hip_atomic_fetch_add(&Cfz[idx], v, __ATOMIC_RELAXED,
                                           __HIP_MEMORY_SCOPE_AGENT);
                } else {  // 3, 4
                    v += Cfz[idx];
                    if (EPI == 3) Cfz[idx] = v;      // x2 f32 (read by LN2 + style resid)
                    if (EPI == 4) Cbz[idx] = f2b(v); // x3 f32 copy is never read: skip store
                }
            }
        }
    }
}

// ---------------- fused GLU GEMM: out = (A@Wv+bv)*sigmoid(A@Wg+bg)*s ----------------
// A bf16 (DMA-staged). B = W^T bf16 [2Nh, K]. grid.z selects pair.
// Same hoisted-addressing counted-vmcnt schedule as gemm_mfma.
template<int TN, bool HAS_S>
__global__ __launch_bounds__(256) void gemm_glu_mfma(
    const ushort* __restrict__ A,
    const ushort* __restrict__ Bt0, const ushort* __restrict__ Bt1,
    ushort* __restrict__ C0, ushort* __restrict__ C1,
    int M, int Nh, int K, int lda,
    const float* __restrict__ bias0, const float* __restrict__ bias1,
    const float* __restrict__ s0, const float* __restrict__ s1, int bofs)
{
    constexpr int WM = (TN == 128) ? 64 : 32;
    constexpr int TI = WM / 16;
    constexpr int BN = TN * 32;
    constexpr int CB = TN / 64;
    constexpr int LP = 2 + 2 * CB;            // gll16 per wave per K-step
    int bx = blockIdx.x, by = blockIdx.y, bz = blockIdx.z;
    xcd_swz(bx, by, bz);
    int z = bz;
    const ushort* Bt = z ? Bt1 : Bt0;
    ushort* Cb = z ? C1 : C0;
    const float* bias = z ? bias1 : bias0;
    const float* s = z ? s1 : s0;

    int m0 = by * 128, n0 = bx * TN;
    __shared__ alignas(16) ushort Al[8192];
    __shared__ alignas(16) ushort B1[2 * BN];
    __shared__ alignas(16) ushort B2[2 * BN];
    int t = threadIdx.x;
    int lane = t & 63, w = t >> 6;
    int wm = (TN == 128) ? (w >> 1) * 64 : w * 32;
    int wn = (TN == 128) ? (w & 1) * 64 : 0;
    int fr = lane & 15, q = lane >> 4;

    // ---- hoisted per-lane staging pointers ----
    int rs = lane >> 2, cbn = lane & 3;
    const ushort* srcA[2]; ushort* dstA[2];
    const ushort* srcU[CB]; ushort* dstU[CB];
    const ushort* srcV[CB]; ushort* dstV[CB];
#pragma unroll
    for (int i = 0; i < 2; i++) {
        int ii = w + 4 * i, row = ii * 16 + rs;
        int kc = (cbn ^ ((row >> 1) & 3)) << 3;
        srcA[i] = A + (long)(m0 + row) * lda + kc;
        dstA[i] = Al + ii * 512;
    }
#pragma unroll
    for (int i = 0; i < CB; i++) {
        int ii = w + 4 * i, row = ii * 16 + rs;
        int kc = (cbn ^ ((row >> 1) & 3)) << 3;
        srcU[i] = Bt + (long)(n0 + row) * K + kc;
        srcV[i] = Bt + (long)(Nh + n0 + row) * K + kc;
        dstU[i] = B1 + ii * 512;
        dstV[i] = B2 + ii * 512;
    }
    auto stage_adv = [&](int b) {
#pragma unroll
        for (int i = 0; i < CB; i++) { gll16(srcU[i], dstU[i] + b * BN); srcU[i] += 32; }
#pragma unroll
        for (int i = 0; i < CB; i++) { gll16(srcV[i], dstV[i] + b * BN); srcV[i] += 32; }
#pragma unroll
        for (int i = 0; i < 2; i++)  { gll16(srcA[i], dstA[i] + b * 4096); srcA[i] += 32; }
    };

    // ---- hoisted swizzled ds_read byte offsets ----
    int offA[TI], offB[4];
#pragma unroll
    for (int ti = 0; ti < TI; ti++) {
        int r = wm + ti * 16 + fr;
        offA[ti] = r * 32 + ((q ^ ((r >> 1) & 3)) << 3);
    }
#pragma unroll
    for (int tj = 0; tj < 4; tj++) {
        int r = wn + tj * 16 + fr;
        offB[tj] = r * 32 + ((q ^ ((r >> 1) & 3)) << 3);
    }

    f4v acc1[TI][4], acc2[TI][4];
#pragma unroll
    for (int i = 0; i < TI; i++)
#pragma unroll
        for (int j = 0; j < 4; j++) { acc1[i][j] = (f4v)(0.0f); acc2[i][j] = (f4v)(0.0f); }

    auto frag_mfma = [&](const ushort* AB, const ushort* BB1, const ushort* BB2) {
        s8v af[TI], b1f[4], b2f[4];
#pragma unroll
        for (int ti = 0; ti < TI; ti++) af[ti] = *(const s8v*)&AB[offA[ti]];
#pragma unroll
        for (int tj = 0; tj < 4; tj++) {
            b1f[tj] = *(const s8v*)&BB1[offB[tj]];
            b2f[tj] = *(const s8v*)&BB2[offB[tj]];
        }
#pragma unroll
        for (int ti = 0; ti < TI; ti++)
#pragma unroll
            for (int tj = 0; tj < 4; tj++) {
                acc1[ti][tj] = __builtin_amdgcn_mfma_f32_16x16x32_bf16(af[ti], b1f[tj], acc1[ti][tj], 0, 0, 0);
                acc2[ti][tj] = __builtin_amdgcn_mfma_f32_16x16x32_bf16(af[ti], b2f[tj], acc2[ti][tj], 0, 0, 0);
            }
    };

    int nt = K >> 5;
    stage_adv(0);
    int cur = 0;
    for (int it = 0; it + 1 < nt; ++it) {
        stage_adv(cur ^ 1);
        waitcnt_vm<LP>();          // tile it landed; tile it+1 stays in flight
        hw_barrier();
        frag_mfma(Al + cur * 4096, B1 + cur * BN, B2 + cur * BN);
        hw_barrier();              // WAR guard for buffer recycle
        cur ^= 1;
    }
    waitcnt_vm<0>();
    hw_barrier();
    frag_mfma(Al + cur * 4096, B1 + cur * BN, B2 + cur * BN);

    int cr0 = q * 4;
#pragma unroll
    for (int ti = 0; ti < TI; ti++) {
        int bb = ((m0 + wm + ti * 16 + cr0) >> 11) + bofs;   // batch = row/2048
#pragma unroll
        for (int tj = 0; tj < 4; tj++) {
            int n = n0 + wn + tj * 16 + fr;
            float bv = bias[n], bg = bias[Nh + n];
            float sv = HAS_S ? s[(long)bb * Nh + n] : 1.0f;
#pragma unroll
            for (int r = 0; r < 4; r++) {
                int m = m0 + wm + ti * 16 + cr0 + r;
                float vv = acc1[ti][tj][r] + bv;
                float gg = acc2[ti][tj][r] + bg;
                float a = vv * (1.0f / (1.0f + __expf(-gg)));
                if (HAS_S) a *= sv;
                Cb[(long)m * Nh + n] = f2b(a);
            }
        }
    }
}

// ---------------- gelu + cast fp32 -> bf16 (elementwise, float4) ----------------
__global__ __launch_bounds__(256) void gelu_cast_kernel(const float* __restrict__ in,
                                                        ushort* __restrict__ out) {
    int i4 = (blockIdx.x * 256 + threadIdx.x) * 4;
    float4 v = *(const float4*)(in + i4);
    ushort4 o;
    o.x = f2b(0.5f * v.x * (1.0f + erff(v.x * 0.70710678118654752440f)));
    o.y = f2b(0.5f * v.y * (1.0f + erff(v.y * 0.70710678118654752440f)));
    o.z = f2b(0.5f * v.z * (1.0f + erff(v.z * 0.70710678118654752440f)));
    o.w = f2b(0.5f * v.w * (1.0f + erff(v.w * 0.70710678118654752440f)));
    *(ushort4*)(out + i4) = o;
}

// ---------------- transpose: src [R,C] (batched) -> dst bf16 [C,R] ----------------
template<bool SRC_F32>
__global__ __launch_bounds__(256) void transpose_kernel(const void* __restrict__ src,
                                                        ushort* __restrict__ dst,
                                                        int R, int C, long sS, long sD) {
    int z = blockIdx.z;
    const void* S = SRC_F32 ? (const void*)((const float*)src + (long)z * sS)
                            : (const void*)((const ushort*)src + (long)z * sS);
    ushort* D = dst + (long)z * sD;
    int r0 = blockIdx.y * 64, c0 = blockIdx.x * 64;
    __shared__ ushort T[64][68];
    int t = threadIdx.x;
#pragma unroll
    for (int p = 0; p < 4; p++) {
        int e = p * 256 + t;
        int row = e >> 4, cc = (e & 15) * 4;
        ushort4 v;
        if (SRC_F32) {
            float4 f = *(const float4*)((const float*)S + (long)(r0 + row) * C + c0 + cc);
            v.x = f2b(f.x); v.y = f2b(f.y); v.z = f2b(f.z); v.w = f2b(f.w);
        } else {
            v = *(const ushort4*)((const ushort*)S + (long)(r0 + row) * C + c0 + cc);
        }
        *(ushort4*)&T[row][cc] = v;
    }
    __syncthreads();
#pragma unroll
    for (int p = 0; p < 4; p++) {
        int e = p * 256 + t;
        int crow = e >> 4, rr = (e & 15) * 4;
        ushort4 o;
        o.x = T[rr + 0][crow]; o.y = T[rr + 1][crow];
        o.z = T[rr + 2][crow]; o.w = T[rr + 3][crow];
        *(ushort4*)&D[(long)(c0 + crow) * R + r0 + rr] = o;
    }
}

// ---------------- merged prep: 8 weight casts + style vectors + LN1 ----------------
// blocks [0,23040): castT; [23040,23112): svec; [23112,39496): LN1 rows
__global__ __launch_bounds__(256) void prep_kernel(
    const float* __restrict__ g1_W, ushort* __restrict__ g1t,
    const float* __restrict__ g2_W, ushort* __restrict__ g2t,
    const float* __restrict__ m1_W, ushort* __restrict__ m1t,
    const float* __restrict__ m2_W, ushort* __restrict__ m2t,
    const float* __restrict__ gs_W, ushort* __restrict__ gst,
    const float* __restrict__ ms_W, ushort* __restrict__ mst,
    const float* __restrict__ r1_W, ushort* __restrict__ r1t,
    const float* __restrict__ r2_W, ushort* __restrict__ r2t,
    const float* __restrict__ w,
    const float* __restrict__ s1W, const float* __restrict__ s1b,
    const float* __restrict__ s2W, const float* __restrict__ s2b,
    const float* __restrict__ ssW, const float* __restrict__ ssb,
    float* __restrict__ sout,
    const float* __restrict__ x,
    const float* __restrict__ ln1_g, const float* __restrict__ ln1_b,
    float* __restrict__ xlnf, ushort* __restrict__ xlnb)
{
    int b = blockIdx.x, t = threadIdx.x;
    if (b < 23040) {
        const float* W; ushort* Wt; int K, N, lo;
        if      (b < 2304)  { W = g1_W; Wt = g1t; K = 768;  N = 768;  lo = 0; }
        else if (b < 4608)  { W = g2_W; Wt = g2t; K = 768;  N = 768;  lo = 2304; }
        else if (b < 5184)  { W = m1_W; Wt = m1t; K = 384;  N = 384;  lo = 4608; }
        else if (b < 5760)  { W = m2_W; Wt = m2t; K = 384;  N = 384;  lo = 5184; }
        else if (b < 14976) { W = gs_W; Wt = gst; K = 768;  N = 3072; lo = 5760; }
        else if (b < 19584) { W = ms_W; Wt = mst; K = 1536; N = 768;  lo = 14976; }
        else if (b < 21888) { W = r1_W; Wt = r1t; K = 768;  N = 768;  lo = 19584; }
        else                { W = r2_W; Wt = r2t; K = 384;  N = 768;  lo = 21888; }
        int local = b - lo, bx = K >> 6;
        int byi = local / bx, bxi = local - byi * bx;
        int k = bxi * 64 + (t & 63), n = byi * 4 + (t >> 6);
        Wt[(long)n * K + k] = f2b(W[(long)k * N + n]);
    } else if (b < 23112) {
        int gid = (b - 23040) * 256 + t;   // 0..18431
        int bb = gid / 2304;
        int r  = gid % 2304;
        const float* w0 = w + (long)bb * 1024;
        const float* w1 = w0 + 512;
        float acc = 0.f;
        if (r < 384) {
            for (int k = 0; k < 512; k++) acc += w0[k] * s1W[k * 384 + r];
            sout[bb * 384 + r] = acc + s1b[r];
        } else if (r < 768) {
            int c = r - 384;
            for (int k = 0; k < 512; k++) acc += w0[k] * s2W[k * 384 + c];
            sout[3072 + bb * 384 + c] = acc + s2b[c];
        } else {
            int c = r - 768;
            for (int k = 0; k < 512; k++) acc += w1[k] * ssW[k * 1536 + c];
            sout[6144 + bb * 1536 + c] = acc + ssb[c];
        }
    } else {
        // LN1 (dual output f32 + bf16), row = b - 23112
        int row = b - 23112;
        const float* xr = x + (long)row * NC;
        float v0 = xr[t], v1 = xr[t + 256], v2 = xr[t + 512];
        float s = v0 + v1 + v2;
        float s2 = v0 * v0 + v1 * v1 + v2 * v2;
        for (int off = 32; off > 0; off >>= 1) {
            s  += __shfl_down(s, off, 64);
            s2 += __shfl_down(s2, off, 64);
        }
        __shared__ float ls[4], ls2[4];
        int wid = t >> 6, lane = t & 63;
        if (lane == 0) { ls[wid] = s; ls2[wid] = s2; }
        __syncthreads();
        if (t == 0) {
            float ts = ls[0] + ls[1] + ls[2] + ls[3];
            float ts2 = ls2[0] + ls2[1] + ls2[2] + ls2[3];
            float mu = ts * (1.0f / NC);
            float var = ts2 * (1.0f / NC) - mu * mu;
            ls[0] = mu;
            ls2[0] = 1.0f / sqrtf(var + 1e-6f);
        }
        __syncthreads();
        float mu = ls[0], r = ls2[0];
#pragma unroll
        for (int i = 0; i < 3; i++) {
            int c = t + i * 256;
            float vv = (i == 0 ? v0 : (i == 1 ? v1 : v2));
            float o = (vv - mu) * r * ln1_g[c] + ln1_b[c];
            xlnf[(long)row * NC + c] = o;
            xlnb[(long)row * NC + c] = f2b(o);
        }
    }
}

// ---------------- LayerNorm (LN2), one block per row of 768; bf16 out ----------------
__global__ __launch_bounds__(256) void ln_kernel(const float* __restrict__ x,
                                                 const float* __restrict__ g,
                                                 const float* __restrict__ b,
                                                 ushort* __restrict__ outb) {
    int row = blockIdx.x;
    const float* xr = x + (long)row * NC;
    int t = threadIdx.x;
    float v0 = xr[t], v1 = xr[t + 256], v2 = xr[t + 512];
    float s = v0 + v1 + v2;
    float s2 = v0 * v0 + v1 * v1 + v2 * v2;
    for (int off = 32; off > 0; off >>= 1) {
        s  += __shfl_down(s, off, 64);
        s2 += __shfl_down(s2, off, 64);
    }
    __shared__ float ls[4], ls2[4];
    int wid = t >> 6, lane = t & 63;
    if (lane == 0) { ls[wid] = s; ls2[wid] = s2; }
    __syncthreads();
    if (t == 0) {
        float ts = ls[0] + ls[1] + ls[2] + ls[3];
        float ts2 = ls2[0] + ls2[1] + ls2[2] + ls2[3];
        float mu = ts * (1.0f / NC);
        float var = ts2 * (1.0f / NC) - mu * mu;
        ls[0] = mu;
        ls2[0] = 1.0f / sqrtf(var + 1e-6f);
    }
    __syncthreads();
    float mu = ls[0], r = ls2[0];
#pragma unroll
    for (int i = 0; i < 3; i++) {
        int c = t + i * 256;
        float vv = (i == 0 ? v0 : (i == 1 ? v1 : v2));
        float o = (vv - mu) * r * g[c] + b[c];
        outb[(long)row * NC + c] = f2b(o);
    }
}

extern "C" void kernel_launch(void* const* d_in, const int* in_sizes, int n_in,
                              void* d_out, int out_size, void* d_ws, size_t ws_size,
                              hipStream_t stream) {
    const float* x     = (const float*)d_in[0];
    const float* w     = (const float*)d_in[1];
    const float* ln1_g = (const float*)d_in[2];
    const float* ln1_b = (const float*)d_in[3];
    const float* ln2_g = (const float*)d_in[4];
    const float* ln2_b = (const float*)d_in[5];
    const float* g1_W  = (const float*)d_in[6];
    const float* g1_b  = (const float*)d_in[7];
    const float* s1_W  = (const float*)d_in[8];
    const float* s1_b  = (const float*)d_in[9];
    const float* m1_W  = (const float*)d_in[10];
    const float* m1_b  = (const float*)d_in[11];
    const float* g2_W  = (const float*)d_in[12];
    const float* g2_b  = (const float*)d_in[13];
    const float* s2_W  = (const float*)d_in[14];
    const float* s2_b  = (const float*)d_in[15];
    const float* m2_W  = (const float*)d_in[16];
    const float* m2_b  = (const float*)d_in[17];
    const float* gs_W  = (const float*)d_in[18];
    const float* gs_b  = (const float*)d_in[19];
    const float* ss_W  = (const float*)d_in[20];
    const float* ss_b  = (const float*)d_in[21];
    const float* ms_W  = (const float*)d_in[22];
    const float* ms_b  = (const float*)d_in[23];
    const float* r1_W  = (const float*)d_in[24];
    const float* r1_b  = (const float*)d_in[25];
    const float* r2_W  = (const float*)d_in[26];
    const float* r2_b  = (const float*)d_in[27];
    float* out = (float*)d_out;
    char* ws = (char*)d_ws;
    char* ob = (char*)d_out;

    // ---- ws layout (74,784,768 B; proven safe) ----
    float*  XLN = (float*)ws;                 // [16384,768] f32: xln -> x2 -> x3
    ushort* A1b = (ushort*)(ws + 50331648);   // 12.6 MB: a1 -> H2 -> AS chunks -> ar
    ushort* g1t = (ushort*)(ws + 62914560);   // W^T bf16 pool
    ushort* g2t = g1t + 589824;
    ushort* m1t = g2t + 589824;
    ushort* m2t = m1t + 147456;
    ushort* gst = m2t + 147456;
    ushort* mst = gst + 2359296;
    ushort* r1t = mst + 1179648;
    ushort* r2t = r1t + 589824;
    float*  SV  = (float*)(ws + 74711040);    // 18432 f32
    ushort* H2n = A1b;                        // h2 output over dead a1 (post-h1)
    ushort* ASq = A1b;                        // [4096,1536] chunk alias (post-step8)
    ushort* ARq = A1b;                        // [16384,384] alias

    // ---- d_out scratch phases ----
    ushort* XLNb  = (ushort*)(ob + 25165824); // p1a: [16384,768] bf16 xln (LN1 .. dual-GLU)
    ushort* XLNT  = (ushort*)(ob + 25165824); // p1b: [8,768,2048] bf16 (T1 .. mix) over XLNb
    ushort* A2q   = (ushort*)(ob + 12582912); // p1: a2 (dual-GLU .. h2)
    ushort* H1Tn  = (ushort*)ob;              // p1: h1^T [8,384,2048] direct from h1 EPI7
    float*  MIXTf = (float*)(ob + 12582912);  // p1: [8,768,384] f32 over dead a2 (mix)
    ushort* MIXTb = (ushort*)(ob + 25165824); // p1: bf16 over XLNT (gelu .. step8)
    ushort* X2LNq = (ushort*)(ob + 25165824); // p2: full ln2 [16384,768] bf16
    ushort* X3q   = (ushort*)ob;              // p2-3: x3 bf16 [16384,768] (over dead H1Tn)

    // 0. merged weight casts + style vectors + LN1 (dual out) in ONE dispatch
    prep_kernel<<<39496, 256, 0, stream>>>(
        g1_W, g1t, g2_W, g2t, m1_W, m1t, m2_W, m2t, gs_W, gst, ms_W, mst,
        r1_W, r1t, r2_W, r2t, w, s1_W, s1_b, s2_W, s2_b, ss_W, ss_b, SV,
        x, ln1_g, ln1_b, XLN, XLNb);

    // 3+5. merged dual-GLU (all-DMA A from XLNb): a1 -> A1b, a2 -> A2q
    gemm_glu_mfma<128, true><<<dim3(3, 128, 2), 256, 0, stream>>>(
        XLNb, g1t, g2t, A1b, A2q, ROWS, 384, 768, 768, g1_b, g2_b, SV, SV + 3072, 0);
    // T1: XLNT = xln^T (reads f32 XLN in ws; overwrites dead XLNb)
    transpose_kernel<true><<<dim3(12, 32, NB), 256, 0, stream>>>(
        XLN, XLNT, 2048, 768, (long)2048 * 768, (long)768 * 2048);
    // 4+T2 fused. h1 = a1@m1, transposed epilogue -> H1Tn (EPI=7)
    gemm_mfma<64, 7, true, false><<<dim3(6, 128), 256, 0, stream>>>(
        A1b, m1t, nullptr, H1Tn, ROWS, 384, 384, 384, 384, 2048, 0, 0, 0, m1_b);
    // 6. h2 = a2@m2 -> H2n (ws, over dead a1)
    gemm_mfma<64, 0, true, false><<<dim3(6, 128), 256, 0, stream>>>(
        A2q, m2t, nullptr, H2n, ROWS, 384, 384, 384, 384, 384, 0, 0, 0, m2_b);
    // 7. mixT(f32) += xlnT@h1T, split-K x4, atomic (H1T read from ob base)
    hipMemsetAsync(MIXTf, 0, (size_t)NB * 768 * 384 * 4, stream);
    gemm_mfma<128, 6, false, true><<<dim3(3, 6, NB * 4), 256, 0, stream>>>(
        XLNT, H1Tn, MIXTf, nullptr, 768, 384, 2048, 2048, 2048, 384,
        (long)768 * 2048, (long)384 * 2048, (long)768 * 384, nullptr);
    // gelu + cast -> MIXTb (over dead XLNT)
    gelu_cast_kernel<<<2304, 256, 0, stream>>>(MIXTf, MIXTb);
    // 8. x2 = xln + h2@mixT^T (f32 in-place); A = H2n in ws
    gemm_mfma<128, 3, false, false><<<dim3(6, 16, NB), 256, 0, stream>>>(
        H2n, MIXTb, XLN, nullptr, 2048, 768, 384, 384, 384, 768,
        (long)2048 * 384, (long)768 * 384, (long)2048 * 768, nullptr);
    // 9. full LN2 -> X2LNq bf16
    ln_kernel<<<ROWS, 256, 0, stream>>>(XLN, ln2_g, ln2_b, X2LNq);
    // 10-11. style branch, 4 chunks of 4096 rows (AS buffer = A1b region; H2 dead)
    for (int ch = 0; ch < 4; ch++) {
        ushort* X2c = X2LNq + (long)ch * 4096 * 768;
        float*  XLNc = XLN + (long)ch * 4096 * 768;
        ushort* X3c = X3q + (long)ch * 4096 * 768;
        gemm_glu_mfma<128, true><<<dim3(12, 32), 256, 0, stream>>>(
            X2c, gst, gst, ASq, ASq, 4096, 1536, 768, 768, gs_b, gs_b,
            SV + 6144, SV + 6144, ch * 2);
        gemm_mfma<128, 4, true, false><<<dim3(6, 32), 256, 0, stream>>>(
            ASq, mst, XLNc, X3c, 4096, 768, 1536, 1536, 1536, 768, 0, 0, 0, ms_b);
    }
    // 12. ar = glu(x3@r1_W) -> ARq
    gemm_glu_mfma<64, false><<<dim3(6, 128), 256, 0, stream>>>(
        X3q, r1t, r1t, ARq, ARq, ROWS, 384, 768, 768, r1_b, r1_b, nullptr, nullptr, 0);
    // 13. out = ar@r2_W + r2_b (fp32 final, overwrites all d_out scratch)
    gemm_mfma<128, 5, true, false><<<dim3(6, 128), 256, 0, stream>>>(
        ARq, r2t, out, nullptr, ROWS, 768, 384, 384, 384, 768, 0, 0, 0, r2_b);
}